// Round 8
// baseline (324.108 us; speedup 1.0000x reference)
//
#include <hip/hip_runtime.h>
#include <stdint.h>

#define NEG (-100.0f)

#define NE 300      // embedding dim
#define NB 64       // batch
#define NL 512      // seq len
#define NP 200      // patterns
#define NH 100      // mlp hidden

#define KP 320      // padded K (300 emb + 1 bias-col + zeros)
#define UNITS 40    // 16B units per row (KP*2/16)
#define ROWB 640    // bytes per row

#define PT 8        // patterns per tile
#define DT 112      // real diag rows per tile (PT*14)
#define DTP 128     // padded B rows per tile (4 col-groups of 32)
#define NTILE 25    // pattern tiles (200/8)
#define NBROWS (NTILE*DTP)   // 3200 padded B rows total
#define LC 32       // l-chunk
#define NCHUNK 16   // 512/32
#define SCW 36      // transposed score tile: sc[col][l], stride 36 floats

#define LDS_A   (LC*ROWB)          // 20480
#define LDS_SC  (DT*SCW*4)         // 16128
#define LDS_TOTAL (2*LDS_A + 2*LDS_SC)   // 73216 -> 2 blocks/CU

using f32x4  = __attribute__((ext_vector_type(4))) float;
using f32x16 = __attribute__((ext_vector_type(16))) float;
using bf16x8 = __attribute__((ext_vector_type(8))) __bf16;

// raw barrier (no compiler vmcnt/lgkmcnt drain) + counted waits (T3/T4)
#define SBAR()       asm volatile("s_barrier" ::: "memory")
#define WAIT_LGKM0() do { asm volatile("s_waitcnt lgkmcnt(0)" ::: "memory"); \
                          __builtin_amdgcn_sched_barrier(0); } while (0)
#define WAIT_VM(N)   do { asm volatile("s_waitcnt vmcnt(" #N ")" ::: "memory"); \
                          __builtin_amdgcn_sched_barrier(0); } while (0)

static __device__ __forceinline__ void gload16(const void* g, void* l) {
    __builtin_amdgcn_global_load_lds(
        (const __attribute__((address_space(1))) void*)g,
        (__attribute__((address_space(3))) void*)l, 16, 0, 0);
}

static __device__ __forceinline__ uint16_t f2bf(float f) {
    union { float f; uint32_t u; } v; v.f = f;
    return (uint16_t)((v.u + 0x7FFFu + ((v.u >> 16) & 1u)) >> 16);   // RNE
}

// keep-alive: forbids rematerialization/demotion of x
static __device__ __forceinline__ void pin(bf16x8& x) {
    asm volatile("" : "+v"(x));
}

// lane i gets lane i-1's value (within rows of 16); row-lane 0 gets 0.
static __device__ __forceinline__ float dpp_shr1(float x) {
    int r = __builtin_amdgcn_update_dpp(0, __float_as_int(x), 0x111, 0xF, 0xF, true);
    return __int_as_float(r);
}

// ---------------------------------------------------------------------------
// prep: gather emb rows by docs, convert to bf16, pad K to 320 (col 300 = 1.0
// for A / bias[d] for B), store 16B units PRE-SWIZZLED (unit j at j^(row&7)).
// B is laid out as [NTILE][128][KP]: tile-local rows 112..127 are zeroed.
// ---------------------------------------------------------------------------
__global__ void prep_kernel(const int* __restrict__ docs,
                            const float* __restrict__ emb,
                            const float* __restrict__ diags,
                            const float* __restrict__ bias,
                            uint16_t* __restrict__ A_ws,
                            uint16_t* __restrict__ B_ws)
{
    int tid = blockIdx.x * blockDim.x + threadIdx.x;
    const int totalA = NB * NL * UNITS;
    const int total  = totalA + NBROWS * UNITS;
    if (tid >= total) return;
    const float* src = nullptr; uint16_t* dst; float extra = 0.0f; int r, j;
    bool valid = true;
    if (tid < totalA) {
        r = tid / UNITS; j = tid - r * UNITS;
        src = emb + (size_t)docs[r] * NE;
        dst = A_ws + (size_t)r * KP;
        extra = 1.0f;                       // bias column multiplier
    } else {
        int t2 = tid - totalA;
        r = t2 / UNITS; j = t2 - r * UNITS;
        dst = B_ws + (size_t)r * KP;
        int lr = r & (DTP - 1);
        if (lr < DT) {
            int dr = (r >> 7) * DT + lr;    // real diag row
            src = diags + (size_t)dr * NE;
            extra = bias[dr];
        } else {
            valid = false;                  // pad row -> zeros
        }
    }
    int jp = j ^ (r & 7);                   // pre-swizzle 16B unit
    union { uint16_t h[8]; uint4 v; } u;
    if (!valid) {
        u.v = uint4{0, 0, 0, 0};
    } else if (j < 37) {                    // e0+7 = 36*8+7 = 295 < 300
        float4 f0 = *reinterpret_cast<const float4*>(src + j * 8);
        float4 f1 = *reinterpret_cast<const float4*>(src + j * 8 + 4);
        u.h[0] = f2bf(f0.x); u.h[1] = f2bf(f0.y);
        u.h[2] = f2bf(f0.z); u.h[3] = f2bf(f0.w);
        u.h[4] = f2bf(f1.x); u.h[5] = f2bf(f1.y);
        u.h[6] = f2bf(f1.z); u.h[7] = f2bf(f1.w);
    } else if (j == 37) {                   // elems 296..299 real, 300 = extra
        float4 f0 = *reinterpret_cast<const float4*>(src + 296);
        u.h[0] = f2bf(f0.x); u.h[1] = f2bf(f0.y);
        u.h[2] = f2bf(f0.z); u.h[3] = f2bf(f0.w);
        u.h[4] = f2bf(extra); u.h[5] = 0; u.h[6] = 0; u.h[7] = 0;
    } else {                                // zero pad
        u.v = uint4{0, 0, 0, 0};
    }
    *reinterpret_cast<uint4*>(dst + (size_t)jp * 8) = u.v;
}

static __device__ __forceinline__ void scan_chunk(const float* __restrict__ sc,
        float& h, float& s, float eps_r, bool is_m0, int i0, int i1)
{
    // preload the whole chunk: xa[l] = sc[i0*SCW + l], xb[l] = sc[i1*SCW + l]
    f32x4 xav[8], xbv[8];
#pragma unroll
    for (int i = 0; i < 8; ++i)
        xav[i] = *reinterpret_cast<const f32x4*>(sc + i0 * SCW + i * 4);
#pragma unroll
    for (int i = 0; i < 8; ++i)
        xbv[i] = *reinterpret_cast<const f32x4*>(sc + i1 * SCW + i * 4);
#pragma unroll
    for (int l = 0; l < LC; ++l) {
        float xa = xav[l >> 2][l & 3];
        float xb = xbv[l >> 2][l & 3];
        float hm1  = dpp_shr1(h);               // h[m-1]
        float t    = is_m0 ? NEG : (hm1 + eps_r);
        float ae   = fmaxf(h, t);               // after_eps[m]
        float aem1 = dpp_shr1(ae);              // after_eps[m-1]
        float mn   = is_m0 ? 0.0f : (aem1 + xb);// main[m] (restart at m=0)
        h = fmaxf(mn, ae + xa);                 // max(main, self_loop)
        s = fmaxf(s, h);                        // only lane m==6 meaningful
    }
}

// ---------------------------------------------------------------------------
// fused GEMM (bf16 MFMA 32x32x16, B resident: breg[20] = 80 VGPR/wave) +
// max-plus scan. 8 waves: 0-3 MFMA (one 32-col group each, dual acc chains),
// 4-5 scan, 6-7 stagers (A double-buffered, issue-early + drain-late).
// LDS 73 KB -> 2 blocks/CU for cross-block latency overlap.
// ---------------------------------------------------------------------------
__global__ __launch_bounds__(512) __attribute__((amdgpu_waves_per_eu(4)))
void sopa_kernel(const uint16_t* __restrict__ A_ws,
                 const uint16_t* __restrict__ B_ws,
                 const float* __restrict__ epsilon,
                 float* __restrict__ scores_g)
{
    extern __shared__ char smem[];
    // LDS layout: [A buf0 | A buf1 | SC buf0 | SC buf1]

    const int blk = blockIdx.x;
    const int bb  = blk / NTILE;
    const int pt  = blk - bb * NTILE;
    const int p0  = pt * PT;

    const int tid  = threadIdx.x;
    const int wave = tid >> 6;
    const int lane = tid & 63;

    if (wave < 4) {
        // ---------------- MFMA persona ----------------
        const int arow  = lane & 31;        // A row within chunk / output l
        const int khalf = lane >> 5;        // k-halves of 16-wide K step
        const int col   = wave * 32 + arow; // output diag-row (padded to 128)
        const int abase = arow * ROWB;
        const int ax3   = arow & 7;
        const bool wr_ok = col < DT;

        // B fragments -> registers, once. 20 frags = 80 VGPR.
        bf16x8 breg[20];
        const uint16_t* Bg = B_ws + ((size_t)pt * DTP + col) * KP;
#pragma unroll
        for (int st = 0; st < 20; ++st) {
            int jp = (st * 2 + khalf) ^ (col & 7);
            breg[st] = *reinterpret_cast<const bf16x8*>(Bg + jp * 8);
            pin(breg[st]);
        }
        SBAR();

        for (int c = 0; c < NCHUNK; ++c) {
            const char* Ab  = smem + (c & 1) * LDS_A;
            float*      scw = (float*)(smem + 2 * LDS_A + (c & 1) * LDS_SC);
            f32x16 acc0, acc1;
#pragma unroll
            for (int i = 0; i < 16; ++i) { acc0[i] = 0.0f; acc1[i] = 0.0f; }
            // two independent acc chains (even/odd k-step) -> MFMA pipelines
#pragma unroll
            for (int sp = 0; sp < 10; ++sp) {
                int jx0 = ((sp * 2) * 2 + khalf) ^ ax3;
                int jx1 = ((sp * 2 + 1) * 2 + khalf) ^ ax3;
                bf16x8 av0 = *reinterpret_cast<const bf16x8*>(Ab + abase + jx0 * 16);
                bf16x8 av1 = *reinterpret_cast<const bf16x8*>(Ab + abase + jx1 * 16);
                acc0 = __builtin_amdgcn_mfma_f32_32x32x16_bf16(av0, breg[sp * 2],     acc0, 0, 0, 0);
                acc1 = __builtin_amdgcn_mfma_f32_32x32x16_bf16(av1, breg[sp * 2 + 1], acc1, 0, 0, 0);
            }
            // C/D: col = lane&31, row = (reg&3) + 8*(reg>>2) + 4*khalf
            if (wr_ok) {
#pragma unroll
                for (int g = 0; g < 4; ++g) {
                    f32x4 v;
                    v[0] = acc0[g * 4 + 0] + acc1[g * 4 + 0];
                    v[1] = acc0[g * 4 + 1] + acc1[g * 4 + 1];
                    v[2] = acc0[g * 4 + 2] + acc1[g * 4 + 2];
                    v[3] = acc0[g * 4 + 3] + acc1[g * 4 + 3];
                    *reinterpret_cast<f32x4*>(scw + col * SCW + g * 8 + khalf * 4) = v;
                }
            }
            WAIT_LGKM0();                    // SC writes visible before barrier
            SBAR();
        }
    } else if (wave < 6) {
        // ---------------- scan persona (4 patterns each) ----------------
        const int  q  = lane >> 3;
        const int  mm = lane & 7;
        const int  pl = ((wave == 5) ? 4 : 0) + (q & 3);   // local pattern 0..7
        const bool is_m0 = (mm == 0);
        float eps_r = 0.0f;
        if (mm >= 1 && mm <= 6) eps_r = epsilon[(p0 + pl) * 6 + (mm - 1)];
        const int i0 = pl * 14 + mm;                       // x[p][0][m]
        const int i1 = pl * 14 + 7 + (mm ? mm - 1 : 0);    // x[p][1][m-1]
        float h = is_m0 ? 0.0f : NEG;
        float s = NEG;

        SBAR();
        for (int c = 0; c < NCHUNK; ++c) {
            if (c > 0) {
                const float* scr = (const float*)(smem + 2 * LDS_A + ((c - 1) & 1) * LDS_SC);
                scan_chunk(scr, h, s, eps_r, is_m0, i0, i1);
            }
            SBAR();
        }
        const float* scr = (const float*)(smem + 2 * LDS_A + ((NCHUNK - 1) & 1) * LDS_SC);
        scan_chunk(scr, h, s, eps_r, is_m0, i0, i1);
        if (q < 4 && mm == 6) scores_g[bb * NP + p0 + pl] = s;
    } else {
        // ---------------- stager persona (double-buffered, issue-early) ----
        const int   wv    = wave & 1;
        const char* a_src = (const char*)(A_ws + (size_t)bb * NL * KP) + wv * 10240 + lane * 16;

        // prologue: stage chunk 0, drain, open
#pragma unroll
        for (int i = 0; i < 10; ++i)
            gload16(a_src + i * 1024, smem + wv * 10240 + i * 1024);
        WAIT_VM(0);
        SBAR();

        for (int c = 0; c < NCHUNK; ++c) {
            if (c + 1 < NCHUNK) {
                // issue chunk c+1 into buf[(c+1)&1] right at period start;
                // ~400cy latency hides under the ~1800cy period; drain late.
                const char* src = a_src + (size_t)(c + 1) * LC * ROWB;
                char*       lb  = smem + ((c + 1) & 1) * LDS_A + wv * 10240;
#pragma unroll
                for (int i = 0; i < 10; ++i)
                    gload16(src + i * 1024, lb + i * 1024);
                WAIT_VM(0);
            }
            SBAR();
        }
    }
}

// ---------------------------------------------------------------------------
// tiny MLP head: one block per batch row, fp32
// ---------------------------------------------------------------------------
__global__ void mlp_kernel(const float* __restrict__ scores_g,
                           const float* __restrict__ w1, const float* __restrict__ b1,
                           const float* __restrict__ w2, const float* __restrict__ b2,
                           const float* __restrict__ w3, const float* __restrict__ b3,
                           float* __restrict__ out)
{
    __shared__ float sc[NP];
    __shared__ float h1[NH];
    __shared__ float h2[NH];
    int b = blockIdx.x, t = threadIdx.x;
    for (int i = t; i < NP; i += blockDim.x) sc[i] = scores_g[b * NP + i];
    __syncthreads();
    if (t < NH) {
        float acc = b1[t];
#pragma unroll 8
        for (int k = 0; k < NP; ++k) acc += sc[k] * w1[k * NH + t];
        h1[t] = fmaxf(acc, 0.0f);
    }
    __syncthreads();
    if (t < NH) {
        float acc = b2[t];
#pragma unroll 8
        for (int k = 0; k < NH; ++k) acc += h1[k] * w2[k * NH + t];
        h2[t] = fmaxf(acc, 0.0f);
    }
    __syncthreads();
    if (t < 64) {
        float l0 = 0.0f, l1 = 0.0f;
        for (int k = t; k < NH; k += 64) {
            float hv = h2[k];
            l0 += hv * w3[k * 2];
            l1 += hv * w3[k * 2 + 1];
        }
#pragma unroll
        for (int off = 32; off > 0; off >>= 1) {
            l0 += __shfl_down(l0, off);
            l1 += __shfl_down(l1, off);
        }
        if (t == 0) {
            l0 += b3[0]; l1 += b3[1];
            float mx  = fmaxf(l0, l1);
            float lse = mx + logf(expf(l0 - mx) + expf(l1 - mx));
            out[b * 2 + 0] = l0 - lse;
            out[b * 2 + 1] = l1 - lse;
        }
    }
}

extern "C" void kernel_launch(void* const* d_in, const int* in_sizes, int n_in,
                              void* d_out, int out_size, void* d_ws, size_t ws_size,
                              hipStream_t stream)
{
    const int*   docs  = (const int*)  d_in[0];
    const float* emb   = (const float*)d_in[1];
    const float* diags = (const float*)d_in[2];
    const float* bias  = (const float*)d_in[3];
    const float* eps   = (const float*)d_in[4];
    const float* w1 = (const float*)d_in[5];
    const float* b1 = (const float*)d_in[6];
    const float* w2 = (const float*)d_in[7];
    const float* b2 = (const float*)d_in[8];
    const float* w3 = (const float*)d_in[9];
    const float* b3 = (const float*)d_in[10];
    float* out = (float*)d_out;

    char* ws = (char*)d_ws;
    uint16_t* A_ws     = (uint16_t*)ws;                              // 20,971,520 B
    uint16_t* B_ws     = (uint16_t*)(ws + 20971520);                 // NBROWS*KP*2 = 2,048,000 B
    float*    scores_g = (float*)   (ws + 20971520 + 2048000);       //     51,200 B

    {
        int totalUnits = (NB * NL + NBROWS) * UNITS;
        int blocks = (totalUnits + 255) / 256;
        prep_kernel<<<blocks, 256, 0, stream>>>(docs, emb, diags, bias, A_ws, B_ws);
    }

    (void)hipFuncSetAttribute(reinterpret_cast<const void*>(sopa_kernel),
                              hipFuncAttributeMaxDynamicSharedMemorySize, LDS_TOTAL);
    sopa_kernel<<<NB * NTILE, 512, LDS_TOTAL, stream>>>(A_ws, B_ws, eps, scores_g);

    mlp_kernel<<<NB, 128, 0, stream>>>(scores_g, w1, b1, w2, b2, w3, b3, out);
}